// Round 8
// baseline (275.086 us; speedup 1.0000x reference)
//
#include <hip/hip_runtime.h>
#include <cstddef>

#define B_ROWS 8192
#define DIM    1024
#define NSESS  32
#define MT     128       // rows per M-tile
#define NTILE  256       // cols per N-tile
#define BK     64        // fp32 per K-chunk per phase = 2 MFMA k-steps
#define KITERS (DIM / BK)   // 16
#define TPE    3         // m-tiles per expert (validated: max expert count <= 384)
#define LROW   72        // shorts per LDS row: 64 bf16 + 8 pad = 144 B (16B-mult)
#define TSZA   (MT * LROW)      // A tile: 128 rows
#define TSZB   (NTILE * LROW)   // B tile: 256 rows
#define NXCD   8
#define EPX    (NSESS / NXCD)        // experts per XCD = 4
#define BPE    (TPE * (DIM / NTILE)) // blocks per expert = 6

typedef __attribute__((ext_vector_type(8))) short short8;
typedef __attribute__((ext_vector_type(4))) float floatx4;
typedef __attribute__((ext_vector_type(4))) int intx4;
typedef __attribute__((ext_vector_type(2))) unsigned int uintx2;

// RNE fp32->bf16 for two values, packed into one dword via v_perm_b32.
__device__ __forceinline__ unsigned pack_bf16_2(float fa, float fb) {
  unsigned a = __builtin_bit_cast(unsigned, fa);
  unsigned b = __builtin_bit_cast(unsigned, fb);
  a += 0x7fffu + ((a >> 16) & 1u);
  b += 0x7fffu + ((b >> 16) & 1u);
  return __builtin_amdgcn_perm(b, a, 0x07060302u); // low = bf16(fa), high = bf16(fb)
}

// Round-13 (ledger r6-r12: bytes, occupancy, L2 locality, tile shape, block
// count, store pattern — all perturbed, time pinned 131-139us. Two-term fit
// across geometries: phase = drain(bytes @ ~16B/cy/CU) + CONSTANT ~5.7k cy.
// The constant = depth-1 pipeline latency: every phase ends in a vmcnt-coupled
// CVTWRITE of loads issued only ~1-2k cycles earlier -> full load round-trip
// exposed, KITERS times. The one depth-2 attempt (r11) spilled (~220 regs in a
// 128-arch cap) and was misread as refuting depth. This round: depth-2 SIZED
// TO FIT:
//  - 512 thr, 128x256 tile (8 waves 2Mx4N, wave tile 64x64, acc[4][4]=64r).
//    In-flight per set = 4+8 float4 = 48r; two sets 96r; est ~150 arch + 64
//    acc = ~214 <= 256 cap (launch_bounds(512,2); arch cap 192, margin ~40).
//  - LDS dbuf 110.6KB -> 1 block/CU (occupancy proven irrelevant, r8).
//  - r11 schedule verbatim: set parity == chunk parity == LDS parity; loads
//    issued 2 full COMPUTE phases before their CVTWRITE drain; counted vmcnt
//    keeps the other set's 12 loads in flight across the barrier.
//  - grid 192 = 32 experts x 3 mtiles x 2 ntiles, XCD-bijective (192%8==0).
//  - keep: ranked compaction, k0/k1 B-prefetch before scan, bf16 LDS +pad,
//    r12 coalesced LDS-transpose epilogue (full 1-KB row segments, no RMW).
// Canaries: WRITE_SIZE ~34MB, VGPR <= ~170 (no spill).
__global__ __launch_bounds__(512, 2) void gemm_kernel(
    const float* __restrict__ x, const float* __restrict__ W,
    const float* __restrict__ bias, const int* __restrict__ sidx,
    float* __restrict__ out)
{
  __shared__ __align__(16) short As0[TSZA], As1[TSZA];
  __shared__ __align__(16) short Bs0[TSZB], Bs1[TSZB];
  __shared__ int row_ids[MT];
  __shared__ int psum[512];

  // ---- XCD-clustered decode ----
  const int hw    = blockIdx.x;          // 0..191, assumed XCD = hw % 8
  const int xcd   = hw & (NXCD - 1);
  const int r     = hw >> 3;             // 0..23: within-XCD sequence
  const int s     = xcd * EPX + (r / BPE);   // expert, clustered per XCD
  const int rr    = r % BPE;             // 0..5
  const int ntile = rr / TPE;            // 0..1 (W slice shared by 3 mtiles)
  const int mtile = rr % TPE;
  const int tid   = threadIdx.x;

  const int lane = tid & 63;
  const int wv   = tid >> 6;            // wave id 0..7
  const int wm   = wv >> 2;             // 0..1 : 64-row half
  const int wn   = wv & 3;              // 0..3 : 64-col quarter
  const int fr   = lane & 15;           // fragment row within 16
  const int kg   = lane >> 4;           // fragment k-group (k = kg*8 + j)

  // ---- staging geometry: 512 thr; instr j covers 32 rows x 256 B ----
  const int srw = tid >> 4;             // 0..31 : row within 32-row group
  const int sch = tid & 15;             // 16-B chunk within 256-B row

  // B byte-offsets + k0/k1 B-loads issued before the sidx scan.
  unsigned boff[8];
  floatx4 wr0[8], wr1[8];
  {
    const unsigned wbyte =
        (unsigned)(((size_t)s * DIM * DIM + (size_t)(ntile * NTILE) * DIM) * 4u);
#pragma unroll
    for (int j = 0; j < 8; ++j) {
      const int tr = j * 32 + srw;
      boff[j] = wbyte + (unsigned)((tr * DIM + sch * 4) * 4);
      wr0[j] = *(const floatx4*)((const char*)W + boff[j]);
    }
#pragma unroll
    for (int j = 0; j < 8; ++j)
      wr1[j] = *(const floatx4*)((const char*)W + boff[j] + (BK * 4));
  }

  // ---- ranked compaction: rows with sidx==s, ranks [mtile*128, +128) ----
  const intx4* sv = (const intx4*)(sidx + tid * 16);
  int c = 0;
#pragma unroll
  for (int j = 0; j < 4; ++j) {
    const intx4 v = sv[j];
#pragma unroll
    for (int e = 0; e < 4; ++e) c += (v[e] == s);
  }
  psum[tid] = c;
  __syncthreads();
#pragma unroll
  for (int d = 1; d < 512; d <<= 1) {
    const int mine = psum[tid];
    const int add  = (tid >= d) ? psum[tid - d] : 0;
    __syncthreads();
    psum[tid] = mine + add;
    __syncthreads();
  }
  const int total = psum[511];
  const int nrows = (total - mtile * MT) < 0 ? 0
                  : ((total - mtile * MT) > MT ? MT : (total - mtile * MT));
  if (nrows == 0) return;               // uniform across block
  const int base_rank = psum[tid] - c;

  if (tid < MT) row_ids[tid] = -1;
  __syncthreads();
  {
    int r2 = base_rank;
    const int lo = mtile * MT, hi = lo + MT;
#pragma unroll
    for (int j = 0; j < 4; ++j) {
      const intx4 v = sv[j];
#pragma unroll
      for (int e = 0; e < 4; ++e) {
        if (v[e] == s) {
          if (r2 >= lo && r2 < hi) row_ids[r2 - lo] = tid * 16 + 4 * j + e;
          ++r2;
        }
      }
    }
  }
  __syncthreads();

  unsigned aoff[4];
  floatx4 xr0[4], xr1[4];
#pragma unroll
  for (int j = 0; j < 4; ++j) {
    int ar = row_ids[j * 32 + srw];
    if (ar < 0) ar = 0;                 // finite dummy; epilogue masks rows >= nrows
    aoff[j] = (unsigned)((ar * DIM + sch * 4) * 4);
    xr0[j] = *(const floatx4*)((const char*)x + aoff[j]);            // k0 A
  }
#pragma unroll
  for (int j = 0; j < 4; ++j)
    xr1[j] = *(const floatx4*)((const char*)x + aoff[j] + (BK * 4)); // k1 A

  floatx4 acc[4][4] = {};

#define LOADSET(XR, WR, KB)                                                    \
  {                                                                            \
    _Pragma("unroll")                                                          \
    for (int j = 0; j < 4; ++j)                                                \
      XR[j] = *(const floatx4*)((const char*)x + aoff[j] + (KB) * (BK * 4));   \
    _Pragma("unroll")                                                          \
    for (int j = 0; j < 8; ++j)                                                \
      WR[j] = *(const floatx4*)((const char*)W + boff[j] + (KB) * (BK * 4));   \
  }

#define CVTWRITE(XR, WR, AS, BS)                                               \
  {                                                                            \
    _Pragma("unroll")                                                          \
    for (int j = 0; j < 4; ++j) {                                              \
      const int off = (j * 32 + srw) * LROW + sch * 4;                         \
      uintx2 ua = { pack_bf16_2(XR[j][0], XR[j][1]),                           \
                    pack_bf16_2(XR[j][2], XR[j][3]) };                         \
      *(uintx2*)&AS[off] = ua;                                                 \
    }                                                                          \
    _Pragma("unroll")                                                          \
    for (int j = 0; j < 8; ++j) {                                              \
      const int off = (j * 32 + srw) * LROW + sch * 4;                         \
      uintx2 ub = { pack_bf16_2(WR[j][0], WR[j][1]),                           \
                    pack_bf16_2(WR[j][2], WR[j][3]) };                         \
      *(uintx2*)&BS[off] = ub;                                                 \
    }                                                                          \
  }

#define COMPUTE(AS, BS)                                                        \
  {                                                                            \
    _Pragma("unroll")                                                          \
    for (int s2 = 0; s2 < 2; ++s2) {                                           \
      short8 fb[4];                                                            \
      _Pragma("unroll")                                                        \
      for (int i = 0; i < 4; ++i)                                              \
        fb[i] = *(const short8*)&BS[(wn * 64 + i * 16 + fr) * LROW + s2 * 32 + kg * 8]; \
      _Pragma("unroll")                                                        \
      for (int mi = 0; mi < 4; ++mi) {                                         \
        const short8 fa = *(const short8*)&AS[(wm * 64 + mi * 16 + fr) * LROW + s2 * 32 + kg * 8]; \
        _Pragma("unroll")                                                      \
        for (int ni = 0; ni < 4; ++ni)                                         \
          acc[mi][ni] = __builtin_amdgcn_mfma_f32_16x16x32_bf16(               \
              fa, fb[ni], acc[mi][ni], 0, 0, 0);                               \
      }                                                                        \
    }                                                                          \
  }

  // prologue: k0 (set0) -> LDS0. set1 (k1) stays in flight.
  CVTWRITE(xr0, wr0, As0, Bs0);
  __syncthreads();

  // Pair loop: even chunks use set0/LDS0, odd chunks set1/LDS1.
  // Each set's loads are issued 2 COMPUTE phases before their CVTWRITE drain.
  for (int kb = 0; kb < KITERS; kb += 2) {
    // phase A: compute k(kb) from LDS0; refill set0 with k(kb+2);
    //          stage set1 (k(kb+1), issued one phase ago) into LDS1
    if (kb + 2 < KITERS) LOADSET(xr0, wr0, kb + 2);
    COMPUTE(As0, Bs0);
    CVTWRITE(xr1, wr1, As1, Bs1);     // counted vmcnt: waits set1 only
    __syncthreads();

    // phase B: compute k(kb+1) from LDS1; refill set1 with k(kb+3);
    //          stage set0 (k(kb+2)) into LDS0
    if (kb + 3 < KITERS) LOADSET(xr1, wr1, kb + 3);
    COMPUTE(As1, Bs1);
    if (kb + 2 < KITERS) {
      CVTWRITE(xr0, wr0, As0, Bs0);   // counted vmcnt: waits set0 only
    }
    __syncthreads();
  }

#undef LOADSET
#undef CVTWRITE
#undef COMPUTE

  // ---- coalesced epilogue (r12, widened to 256 cols / 512 thr) ------------
  // acc: tile row = wm*64 + mi*16 + kg*4 + q, col = wn*64 + ni*16 + fr.
  // 4 passes of 32 rows via [32][260] f32 LDS aliased onto Bs0 (33280 B).
  // One dwordx4 store instr = 64 lanes x 16 B = one FULL 1-KB output row.
  __syncthreads();                     // all COMPUTE reads of LDS done
  float* obuf = (float*)Bs0;           // 32*260*4 = 33280 B <= 36864 B
  const int col0 = ntile * NTILE + wn * 64;
  float bv[4];
#pragma unroll
  for (int ni = 0; ni < 4; ++ni) bv[ni] = bias[s * DIM + col0 + ni * 16 + fr];

  const int rbase = tid >> 6;          // 0..7 : row within 8-row store group
  const int ch    = tid & 63;          // 16-B chunk within 1-KB row

#pragma unroll
  for (int p = 0; p < 4; ++p) {
    if (wm == (p >> 1)) {
#pragma unroll
      for (int mh = 0; mh < 2; ++mh) {
        const int mi = (p & 1) * 2 + mh;
        const int lr = mi * 16 + kg * 4 - (p & 1) * 32;   // 0..28 local row base
#pragma unroll
        for (int q = 0; q < 4; ++q)
#pragma unroll
          for (int ni = 0; ni < 4; ++ni)
            obuf[(lr + q) * 260 + wn * 64 + ni * 16 + fr] = acc[mi][ni][q] + bv[ni];
      }
    }
    __syncthreads();
#pragma unroll
    for (int j = 0; j < 4; ++j) {
      const int lr = j * 8 + rbase;              // 0..31
      const int ml = p * 32 + lr;                // tile row
      if (ml < nrows) {
        const int orow = row_ids[ml];
        const floatx4 v = *(const floatx4*)&obuf[lr * 260 + ch * 4];
        *(floatx4*)&out[(size_t)orow * DIM + ntile * NTILE + ch * 4] = v;
      }
    }
    __syncthreads();
  }
}

extern "C" void kernel_launch(void* const* d_in, const int* in_sizes, int n_in,
                              void* d_out, int out_size, void* d_ws, size_t ws_size,
                              hipStream_t stream) {
  const float* x    = (const float*)d_in[0];
  const float* W    = (const float*)d_in[1];
  const float* b    = (const float*)d_in[2];
  const int*   sidx = (const int*)d_in[3];
  float* out = (float*)d_out;
  (void)d_ws; (void)ws_size;  // OFF-LIMITS: any ws touch => 512MiB re-poison
                              // fill (~80us) per iteration (r9 post-mortem)

  hipLaunchKernelGGL(gemm_kernel, dim3(NSESS * TPE * (DIM / NTILE)), dim3(512),
                     0, stream, x, W, b, sidx, out);
}

// Round 9
// 273.298 us; speedup vs baseline: 1.0065x; 1.0065x over previous
//
#include <hip/hip_runtime.h>
#include <cstddef>

#define B_ROWS 8192
#define DIM    1024
#define NSESS  32
#define MT     128       // rows per M-tile
#define NTILE  256       // cols per N-tile
#define BK     64        // fp32 per K-chunk per phase = 2 MFMA k-steps
#define KITERS (DIM / BK)   // 16
#define TPE    3         // m-tiles per expert (validated: max expert count <= 384)
#define LROW   72        // shorts per LDS row: 64 bf16 + 8 pad = 144 B (16B-mult)
#define TSZA   (MT * LROW)      // A tile: 128 rows
#define TSZB   (NTILE * LROW)   // B tile: 256 rows
#define NXCD   8
#define EPX    (NSESS / NXCD)        // experts per XCD = 4
#define BPE    (TPE * (DIM / NTILE)) // blocks per expert = 12

typedef __attribute__((ext_vector_type(8))) short short8;
typedef __attribute__((ext_vector_type(4))) float floatx4;
typedef __attribute__((ext_vector_type(4))) int intx4;
typedef __attribute__((ext_vector_type(2))) unsigned int uintx2;

// RNE fp32->bf16 for two values, packed into one dword via v_perm_b32.
__device__ __forceinline__ unsigned pack_bf16_2(float fa, float fb) {
  unsigned a = __builtin_bit_cast(unsigned, fa);
  unsigned b = __builtin_bit_cast(unsigned, fb);
  a += 0x7fffu + ((a >> 16) & 1u);
  b += 0x7fffu + ((b >> 16) & 1u);
  return __builtin_amdgcn_perm(b, a, 0x07060302u); // low = bf16(fa), high = bf16(fb)
}

// Barrier WITHOUT the vmcnt(0) drain. __syncthreads() lowers its workgroup
// fence to s_waitcnt vmcnt(0) lgkmcnt(0) + s_barrier, draining ALL in-flight
// global loads every phase — this was the config-invariant ~5.7k cy/phase
// constant of rounds 6-13 (bytes/occupancy/locality/tile/depth all flat).
// Raw s_barrier + lgkmcnt(0) keeps LDS visibility (ds ops drained) while the
// prefetched register set's global loads stay in flight across the barrier
// (m201/m218 pattern: +38-73% on the learn-loop GEMM).
#define KBAR()                                                                 \
  {                                                                            \
    asm volatile("s_waitcnt lgkmcnt(0)" ::: "memory");                         \
    __builtin_amdgcn_s_barrier();                                              \
  }

// Round-14 (post-mortem r13: depth-2 sized-to-fit gained 137->119us, no spill
// — but only ~half the prediction. Root cause found in the guide's compiler
// facts: every __syncthreads() drains vmcnt to 0, so NO round's prefetch ever
// survived a barrier; "depth-2" was depth-0.5. This round = r13 VERBATIM with
// every __syncthreads replaced by KBAR (lgkmcnt(0) + raw s_barrier). All
// barrier sites are block-uniform; no cross-wave global-store visibility is
// needed anywhere (LDS-only communication), so semantics are preserved.)
__global__ __launch_bounds__(512, 2) void gemm_kernel(
    const float* __restrict__ x, const float* __restrict__ W,
    const float* __restrict__ bias, const int* __restrict__ sidx,
    float* __restrict__ out)
{
  __shared__ __align__(16) short As0[TSZA], As1[TSZA];
  __shared__ __align__(16) short Bs0[TSZB], Bs1[TSZB];
  __shared__ int row_ids[MT];
  __shared__ int psum[512];

  // ---- XCD-clustered decode ----
  const int hw    = blockIdx.x;          // 0..383, assumed XCD = hw % 8
  const int xcd   = hw & (NXCD - 1);
  const int r     = hw >> 3;             // 0..47: within-XCD sequence
  const int s     = xcd * EPX + (r / BPE);   // expert, clustered per XCD
  const int rr    = r % BPE;             // 0..11
  const int ntile = rr / TPE;            // 0..3 (W slice shared by 3 mtiles)
  const int mtile = rr % TPE;
  const int tid   = threadIdx.x;

  const int lane = tid & 63;
  const int wv   = tid >> 6;            // wave id 0..7
  const int wm   = wv >> 2;             // 0..1 : 64-row half
  const int wn   = wv & 3;              // 0..3 : 64-col quarter
  const int fr   = lane & 15;           // fragment row within 16
  const int kg   = lane >> 4;           // fragment k-group (k = kg*8 + j)

  // ---- staging geometry: 512 thr; instr j covers 32 rows x 256 B ----
  const int srw = tid >> 4;             // 0..31 : row within 32-row group
  const int sch = tid & 15;             // 16-B chunk within 256-B row

  // B byte-offsets + k0/k1 B-loads issued before the sidx scan.
  unsigned boff[8];
  floatx4 wr0[8], wr1[8];
  {
    const unsigned wbyte =
        (unsigned)(((size_t)s * DIM * DIM + (size_t)(ntile * NTILE) * DIM) * 4u);
#pragma unroll
    for (int j = 0; j < 8; ++j) {
      const int tr = j * 32 + srw;
      boff[j] = wbyte + (unsigned)((tr * DIM + sch * 4) * 4);
      wr0[j] = *(const floatx4*)((const char*)W + boff[j]);
    }
#pragma unroll
    for (int j = 0; j < 8; ++j)
      wr1[j] = *(const floatx4*)((const char*)W + boff[j] + (BK * 4));
  }

  // ---- ranked compaction: rows with sidx==s, ranks [mtile*128, +128) ----
  const intx4* sv = (const intx4*)(sidx + tid * 16);
  int c = 0;
#pragma unroll
  for (int j = 0; j < 4; ++j) {
    const intx4 v = sv[j];
#pragma unroll
    for (int e = 0; e < 4; ++e) c += (v[e] == s);
  }
  psum[tid] = c;
  KBAR();
#pragma unroll
  for (int d = 1; d < 512; d <<= 1) {
    const int mine = psum[tid];
    const int add  = (tid >= d) ? psum[tid - d] : 0;
    KBAR();
    psum[tid] = mine + add;
    KBAR();
  }
  const int total = psum[511];
  const int nrows = (total - mtile * MT) < 0 ? 0
                  : ((total - mtile * MT) > MT ? MT : (total - mtile * MT));
  if (nrows == 0) return;               // uniform across block
  const int base_rank = psum[tid] - c;

  if (tid < MT) row_ids[tid] = -1;
  KBAR();
  {
    int r2 = base_rank;
    const int lo = mtile * MT, hi = lo + MT;
#pragma unroll
    for (int j = 0; j < 4; ++j) {
      const intx4 v = sv[j];
#pragma unroll
      for (int e = 0; e < 4; ++e) {
        if (v[e] == s) {
          if (r2 >= lo && r2 < hi) row_ids[r2 - lo] = tid * 16 + 4 * j + e;
          ++r2;
        }
      }
    }
  }
  KBAR();

  unsigned aoff[4];
  floatx4 xr0[4], xr1[4];
#pragma unroll
  for (int j = 0; j < 4; ++j) {
    int ar = row_ids[j * 32 + srw];
    if (ar < 0) ar = 0;                 // finite dummy; epilogue masks rows >= nrows
    aoff[j] = (unsigned)((ar * DIM + sch * 4) * 4);
    xr0[j] = *(const floatx4*)((const char*)x + aoff[j]);            // k0 A
  }
#pragma unroll
  for (int j = 0; j < 4; ++j)
    xr1[j] = *(const floatx4*)((const char*)x + aoff[j] + (BK * 4)); // k1 A

  floatx4 acc[4][4] = {};

#define LOADSET(XR, WR, KB)                                                    \
  {                                                                            \
    _Pragma("unroll")                                                          \
    for (int j = 0; j < 4; ++j)                                                \
      XR[j] = *(const floatx4*)((const char*)x + aoff[j] + (KB) * (BK * 4));   \
    _Pragma("unroll")                                                          \
    for (int j = 0; j < 8; ++j)                                                \
      WR[j] = *(const floatx4*)((const char*)W + boff[j] + (KB) * (BK * 4));   \
  }

#define CVTWRITE(XR, WR, AS, BS)                                               \
  {                                                                            \
    _Pragma("unroll")                                                          \
    for (int j = 0; j < 4; ++j) {                                              \
      const int off = (j * 32 + srw) * LROW + sch * 4;                         \
      uintx2 ua = { pack_bf16_2(XR[j][0], XR[j][1]),                           \
                    pack_bf16_2(XR[j][2], XR[j][3]) };                         \
      *(uintx2*)&AS[off] = ua;                                                 \
    }                                                                          \
    _Pragma("unroll")                                                          \
    for (int j = 0; j < 8; ++j) {                                              \
      const int off = (j * 32 + srw) * LROW + sch * 4;                         \
      uintx2 ub = { pack_bf16_2(WR[j][0], WR[j][1]),                           \
                    pack_bf16_2(WR[j][2], WR[j][3]) };                         \
      *(uintx2*)&BS[off] = ub;                                                 \
    }                                                                          \
  }

#define COMPUTE(AS, BS)                                                        \
  {                                                                            \
    _Pragma("unroll")                                                          \
    for (int s2 = 0; s2 < 2; ++s2) {                                           \
      short8 fb[4];                                                            \
      _Pragma("unroll")                                                        \
      for (int i = 0; i < 4; ++i)                                              \
        fb[i] = *(const short8*)&BS[(wn * 64 + i * 16 + fr) * LROW + s2 * 32 + kg * 8]; \
      _Pragma("unroll")                                                        \
      for (int mi = 0; mi < 4; ++mi) {                                         \
        const short8 fa = *(const short8*)&AS[(wm * 64 + mi * 16 + fr) * LROW + s2 * 32 + kg * 8]; \
        _Pragma("unroll")                                                      \
        for (int ni = 0; ni < 4; ++ni)                                         \
          acc[mi][ni] = __builtin_amdgcn_mfma_f32_16x16x32_bf16(               \
              fa, fb[ni], acc[mi][ni], 0, 0, 0);                               \
      }                                                                        \
    }                                                                          \
  }

  // prologue: k0 (set0) -> LDS0. set1 (k1) stays in flight.
  CVTWRITE(xr0, wr0, As0, Bs0);
  KBAR();

  // Pair loop: even chunks use set0/LDS0, odd chunks set1/LDS1.
  // Each set's loads are issued 2 COMPUTE phases before their CVTWRITE drain;
  // with KBAR (no vmcnt drain) they genuinely stay in flight across barriers.
  for (int kb = 0; kb < KITERS; kb += 2) {
    // phase A: compute k(kb) from LDS0; refill set0 with k(kb+2);
    //          stage set1 (k(kb+1), issued one phase ago) into LDS1
    if (kb + 2 < KITERS) LOADSET(xr0, wr0, kb + 2);
    COMPUTE(As0, Bs0);
    CVTWRITE(xr1, wr1, As1, Bs1);     // compiler's counted vmcnt: set1 only
    KBAR();

    // phase B: compute k(kb+1) from LDS1; refill set1 with k(kb+3);
    //          stage set0 (k(kb+2)) into LDS0
    if (kb + 3 < KITERS) LOADSET(xr1, wr1, kb + 3);
    COMPUTE(As1, Bs1);
    if (kb + 2 < KITERS) {
      CVTWRITE(xr0, wr0, As0, Bs0);   // compiler's counted vmcnt: set0 only
    }
    KBAR();
  }

#undef LOADSET
#undef CVTWRITE
#undef COMPUTE

  // ---- coalesced epilogue (r12, widened to 256 cols / 512 thr) ------------
  // acc: tile row = wm*64 + mi*16 + kg*4 + q, col = wn*64 + ni*16 + fr.
  // 4 passes of 32 rows via [32][260] f32 LDS aliased onto Bs0 (33280 B).
  // One dwordx4 store instr = 64 lanes x 16 B = one FULL 1-KB output row.
  KBAR();                              // all COMPUTE reads of LDS done
  float* obuf = (float*)Bs0;           // 32*260*4 = 33280 B <= 36864 B
  const int col0 = ntile * NTILE + wn * 64;
  float bv[4];
#pragma unroll
  for (int ni = 0; ni < 4; ++ni) bv[ni] = bias[s * DIM + col0 + ni * 16 + fr];

  const int rbase = tid >> 6;          // 0..7 : row within 8-row store group
  const int ch    = tid & 63;          // 16-B chunk within 1-KB row

#pragma unroll
  for (int p = 0; p < 4; ++p) {
    if (wm == (p >> 1)) {
#pragma unroll
      for (int mh = 0; mh < 2; ++mh) {
        const int mi = (p & 1) * 2 + mh;
        const int lr = mi * 16 + kg * 4 - (p & 1) * 32;   // 0..28 local row base
#pragma unroll
        for (int q = 0; q < 4; ++q)
#pragma unroll
          for (int ni = 0; ni < 4; ++ni)
            obuf[(lr + q) * 260 + wn * 64 + ni * 16 + fr] = acc[mi][ni][q] + bv[ni];
      }
    }
    KBAR();
#pragma unroll
    for (int j = 0; j < 4; ++j) {
      const int lr = j * 8 + rbase;              // 0..31
      const int ml = p * 32 + lr;                // tile row
      if (ml < nrows) {
        const int orow = row_ids[ml];
        const floatx4 v = *(const floatx4*)&obuf[lr * 260 + ch * 4];
        *(floatx4*)&out[(size_t)orow * DIM + ntile * NTILE + ch * 4] = v;
      }
    }
    KBAR();
  }
}

extern "C" void kernel_launch(void* const* d_in, const int* in_sizes, int n_in,
                              void* d_out, int out_size, void* d_ws, size_t ws_size,
                              hipStream_t stream) {
  const float* x    = (const float*)d_in[0];
  const float* W    = (const float*)d_in[1];
  const float* b    = (const float*)d_in[2];
  const int*   sidx = (const int*)d_in[3];
  float* out = (float*)d_out;
  (void)d_ws; (void)ws_size;  // OFF-LIMITS: any ws touch => 512MiB re-poison
                              // fill (~80us) per iteration (r9 post-mortem)

  hipLaunchKernelGGL(gemm_kernel, dim3(NSESS * TPE * (DIM / NTILE)), dim3(512),
                     0, stream, x, W, b, sidx, out);
}